// Round 11
// baseline (321.318 us; speedup 1.0000x reference)
//
#include <hip/hip_runtime.h>
#include <math.h>

// Problem constants (from reference)
constexpr int N_NODES = 50000;
constexpr int E_EDGES = 800000;
constexpr int E_TOT   = E_EDGES + N_NODES;   // 850000 with self loops
constexpr int D_IN    = 128;
constexpr int D_HID   = 64;   // HID == OUT == 64
constexpr float NEG_SLOPE = 0.2f;

constexpr int SCAN_B  = 256;
constexpr int SCAN_NB = (N_NODES + SCAN_B - 1) / SCAN_B;   // 196

// ---------------- CSR build ----------------

// one pass over the edge list: histogram of dst + emit edge_index-with-self-loops
__global__ __launch_bounds__(256)
void k_hist_ei(const int* __restrict__ ei, int* __restrict__ counts,
               float* __restrict__ out_ei) {
    int k = blockIdx.x * blockDim.x + threadIdx.x;
    if (k >= E_TOT) return;
    int src, dst;
    if (k < E_EDGES) { src = ei[k]; dst = ei[E_EDGES + k]; }
    else             { src = dst = k - E_EDGES; }
    out_ei[k]         = (float)src;
    out_ei[E_TOT + k] = (float)dst;
    atomicAdd(&counts[dst], 1);
}

// scan phase A: per-block sums of counts
__global__ __launch_bounds__(256)
void k_scan_a(const int* __restrict__ counts, int* __restrict__ blocksum) {
    int i = blockIdx.x * SCAN_B + threadIdx.x;
    int lane = threadIdx.x & 63, wave = threadIdx.x >> 6;
    int v = (i < N_NODES) ? counts[i] : 0;
    #pragma unroll
    for (int off = 32; off; off >>= 1) v += __shfl_xor(v, off);
    __shared__ int ws[4];
    if (lane == 0) ws[wave] = v;
    __syncthreads();
    if (threadIdx.x == 0)
        blocksum[blockIdx.x] = ws[0] + ws[1] + ws[2] + ws[3];
}

// scan phase B: single small block scans the 196 block sums (exclusive, in place)
__global__ __launch_bounds__(256)
void k_scan_b(int* __restrict__ blocksum, int* __restrict__ rowptr) {
    __shared__ int s[SCAN_B];
    int t = threadIdx.x;
    int v = (t < SCAN_NB) ? blocksum[t] : 0;
    s[t] = v;
    __syncthreads();
    #pragma unroll
    for (int off = 1; off < SCAN_B; off <<= 1) {
        int u = (t >= off) ? s[t - off] : 0;
        __syncthreads();
        s[t] += u;
        __syncthreads();
    }
    if (t < SCAN_NB) blocksum[t] = s[t] - v;      // exclusive block base
    if (t == SCAN_B - 1) rowptr[N_NODES] = s[SCAN_B - 1];   // grand total == E_TOT
}

// scan phase C: in-block exclusive scan + block base -> rowptr & cursor init
__global__ __launch_bounds__(256)
void k_scan_c(int* __restrict__ counts_cursor, const int* __restrict__ blocksum,
              int* __restrict__ rowptr) {
    __shared__ int s[SCAN_B];
    int t = threadIdx.x;
    int i = blockIdx.x * SCAN_B + t;
    int v = (i < N_NODES) ? counts_cursor[i] : 0;
    s[t] = v;
    __syncthreads();
    #pragma unroll
    for (int off = 1; off < SCAN_B; off <<= 1) {
        int u = (t >= off) ? s[t - off] : 0;
        __syncthreads();
        s[t] += u;
        __syncthreads();
    }
    if (i < N_NODES) {
        int excl = s[t] - v + blocksum[blockIdx.x];
        rowptr[i] = excl;
        counts_cursor[i] = excl;   // cursor init (aliases counts)
    }
}

// scatter: write ONLY csr_eid (4B/edge) — src is re-derived in k_agg from ei.
// (Round-8 profile: scattering src+eid caused 84 MB of line-ping-pong
// writebacks across XCDs; halving scattered bytes halves that.)
__global__ __launch_bounds__(256)
void k_scatter(const int* __restrict__ ei, int* __restrict__ cursor,
               int* __restrict__ csr_eid) {
    int k = blockIdx.x * blockDim.x + threadIdx.x;
    if (k >= E_TOT) return;
    int dst = (k < E_EDGES) ? ei[E_EDGES + k] : (k - E_EDGES);
    int pos = atomicAdd(&cursor[dst], 1);
    csr_eid[pos] = k;
}

// ---------------- dense: h = x @ W  (+ per-node attention logits) ----------------
// Register-tiled GEMM: block = 256 threads -> 64 nodes x 64 cols tile.
// W^T staged in padded LDS (stride K+4: 16B-aligned b128 reads, 2-way bank
// aliasing = free). Each thread owns a 4x4 tile: per 4-k step, 4 global
// float4 x-loads (broadcast across 16 lanes) + 4 ds_read_b128 + 64 fma.

template<int K>
__global__ __launch_bounds__(256)
void k_gemm_t(const float* __restrict__ xin, const float* __restrict__ Wg,
              const float* __restrict__ a_s, const float* __restrict__ a_d,
              float* __restrict__ h, float* __restrict__ es, float* __restrict__ ed) {
    __shared__ float wt[64][K + 4];   // wt[col][k] = Wg[k][col]
    const int t = threadIdx.x;
    const int lane = t & 63, wid = t >> 6;
    for (int k = wid; k < K; k += 4)
        wt[lane][k] = Wg[k * 64 + lane];
    __syncthreads();

    const int cg = t & 15, ng = t >> 4;
    const int c0 = cg * 4;
    const int node0 = blockIdx.x * 64 + ng * 4;
    if (node0 >= N_NODES) return;    // N_NODES % 4 == 0: all-or-nothing per thread
    const float* xrow = xin + (size_t)node0 * K;

    float acc[4][4];
    #pragma unroll
    for (int n = 0; n < 4; ++n)
        #pragma unroll
        for (int i = 0; i < 4; ++i) acc[n][i] = 0.f;

    #pragma unroll 4
    for (int k = 0; k < K; k += 4) {
        float4 xv[4], wv[4];
        #pragma unroll
        for (int n = 0; n < 4; ++n) xv[n] = *(const float4*)(xrow + n * K + k);
        #pragma unroll
        for (int i = 0; i < 4; ++i) wv[i] = *(const float4*)(&wt[c0 + i][k]);
        #pragma unroll
        for (int n = 0; n < 4; ++n) {
            #pragma unroll
            for (int i = 0; i < 4; ++i) {
                acc[n][i] = fmaf(xv[n].x, wv[i].x, acc[n][i]);
                acc[n][i] = fmaf(xv[n].y, wv[i].y, acc[n][i]);
                acc[n][i] = fmaf(xv[n].z, wv[i].z, acc[n][i]);
                acc[n][i] = fmaf(xv[n].w, wv[i].w, acc[n][i]);
            }
        }
    }

    const float4 as4 = *(const float4*)(a_s + c0);
    const float4 ad4 = *(const float4*)(a_d + c0);
    #pragma unroll
    for (int n = 0; n < 4; ++n) {
        float4 hv = make_float4(acc[n][0], acc[n][1], acc[n][2], acc[n][3]);
        *(float4*)(h + (size_t)(node0 + n) * D_HID + c0) = hv;
        float vs = acc[n][0] * as4.x + acc[n][1] * as4.y
                 + acc[n][2] * as4.z + acc[n][3] * as4.w;
        float vd = acc[n][0] * ad4.x + acc[n][1] * ad4.y
                 + acc[n][2] * ad4.z + acc[n][3] * ad4.w;
        #pragma unroll
        for (int off = 8; off; off >>= 1) {   // butterfly across the 16 col-lanes
            vs += __shfl_xor(vs, off);
            vd += __shfl_xor(vd, off);
        }
        if (cg == 0) { es[node0 + n] = vs; ed[node0 + n] = vd; }
    }
}

// ---------------- sparse: segment softmax + weighted aggregation ----------------
// one wave per destination node; src derived from csr_eid via ei

template<bool RELU, bool WRITE_ALPHA>
__global__ __launch_bounds__(256)
void k_agg(const float* __restrict__ h, const float* __restrict__ es,
           const float* __restrict__ ed, const int* __restrict__ rowptr,
           const int* __restrict__ csr_eid, const int* __restrict__ ei,
           const float* __restrict__ bias, float* __restrict__ out,
           float* __restrict__ alpha_out) {
    int wave = threadIdx.x >> 6, lane = threadIdx.x & 63;
    int node = blockIdx.x * 4 + wave;
    if (node >= N_NODES) return;
    int lo  = __builtin_amdgcn_readfirstlane(rowptr[node]);
    int deg = __builtin_amdgcn_readfirstlane(rowptr[node + 1]) - lo;
    float edv = ed[node];

    if (deg <= 64) {
        // ---- fast path: lane-parallel logits, register-resident softmax ----
        int   s = 0, eid = 0;
        float e = -INFINITY;
        if (lane < deg) {
            eid = csr_eid[lo + lane];
            s   = (eid < E_EDGES) ? ei[eid] : (eid - E_EDGES);
            e = es[s] + edv;
            e = (e >= 0.f) ? e : NEG_SLOPE * e;
        }
        float m = e;
        #pragma unroll
        for (int off = 32; off; off >>= 1) m = fmaxf(m, __shfl_xor(m, off));
        float ex = (lane < deg) ? __expf(e - m) : 0.f;
        float z = ex;
        #pragma unroll
        for (int off = 32; off; off >>= 1) z += __shfl_xor(z, off);
        float inv = 1.f / z;

        // 4 independent fma/load chains for memory-level parallelism
        float a0 = 0.f, a1 = 0.f, a2 = 0.f, a3 = 0.f;
        int j = 0;
        for (; j + 4 <= deg; j += 4) {
            int   s0 = __shfl(s, j),     s1 = __shfl(s, j + 1);
            int   s2 = __shfl(s, j + 2), s3 = __shfl(s, j + 3);
            float e0 = __shfl(ex, j),     e1 = __shfl(ex, j + 1);
            float e2 = __shfl(ex, j + 2), e3 = __shfl(ex, j + 3);
            a0 = fmaf(e0, h[s0 * D_HID + lane], a0);
            a1 = fmaf(e1, h[s1 * D_HID + lane], a1);
            a2 = fmaf(e2, h[s2 * D_HID + lane], a2);
            a3 = fmaf(e3, h[s3 * D_HID + lane], a3);
        }
        for (; j < deg; ++j) {
            int   sj  = __shfl(s, j);
            float exj = __shfl(ex, j);
            a0 = fmaf(exj, h[sj * D_HID + lane], a0);
        }
        float acc = (a0 + a1) + (a2 + a3);
        float res = fmaf(acc, inv, bias[lane]);
        if (RELU) res = fmaxf(res, 0.f);
        out[node * D_HID + lane] = res;
        if (WRITE_ALPHA && lane < deg) alpha_out[eid] = ex * inv;
    } else {
        // ---- fallback: serial 3-pass (degree > 64; effectively never) ----
        int hi = lo + deg;
        float m = -INFINITY;
        for (int j = lo; j < hi; ++j) {
            int eid = csr_eid[j];
            int s   = (eid < E_EDGES) ? ei[eid] : (eid - E_EDGES);
            float e = es[s] + edv;
            e = (e >= 0.f) ? e : NEG_SLOPE * e;
            m = fmaxf(m, e);
        }
        float z = 0.f, acc = 0.f;
        for (int j = lo; j < hi; ++j) {
            int eid = csr_eid[j];
            int s   = (eid < E_EDGES) ? ei[eid] : (eid - E_EDGES);
            float e = es[s] + edv;
            e = (e >= 0.f) ? e : NEG_SLOPE * e;
            float ex = __expf(e - m);
            z += ex;
            acc = fmaf(ex, h[s * D_HID + lane], acc);
        }
        float inv = 1.f / z;
        float res = fmaf(acc, inv, bias[lane]);
        if (RELU) res = fmaxf(res, 0.f);
        out[node * D_HID + lane] = res;
        if (WRITE_ALPHA) {
            for (int j = lo + lane; j < hi; j += 64) {
                int eid = csr_eid[j];
                int s   = (eid < E_EDGES) ? ei[eid] : (eid - E_EDGES);
                float e = es[s] + edv;
                e = (e >= 0.f) ? e : NEG_SLOPE * e;
                alpha_out[eid] = __expf(e - m) * inv;
            }
        }
    }
}

// ---------------- launch ----------------

extern "C" void kernel_launch(void* const* d_in, const int* in_sizes, int n_in,
                              void* d_out, int out_size, void* d_ws, size_t ws_size,
                              hipStream_t stream) {
    const float* x    = (const float*)d_in[0];
    const int*   ei   = (const int*)d_in[1];
    const float* W1   = (const float*)d_in[2];
    const float* as1  = (const float*)d_in[3];
    const float* ad1  = (const float*)d_in[4];
    const float* b1   = (const float*)d_in[5];
    const float* W2   = (const float*)d_in[6];
    const float* as2  = (const float*)d_in[7];
    const float* ad2  = (const float*)d_in[8];
    const float* b2   = (const float*)d_in[9];
    float* out = (float*)d_out;

    // carve workspace (~30 MB)
    size_t off = 0;
    auto carve = [&](size_t bytes) -> void* {
        void* p = (char*)d_ws + off;
        off += (bytes + 255) & ~(size_t)255;
        return p;
    };
    int*   cursor   = (int*)carve((size_t)N_NODES * 4);          // counts, then cursor
    int*   rowptr   = (int*)carve((size_t)(N_NODES + 1) * 4);
    int*   blocksum = (int*)carve((size_t)SCAN_NB * 4);
    int*   csr_eid  = (int*)carve((size_t)E_TOT * 4);
    float* h1       = (float*)carve((size_t)N_NODES * D_HID * 4); // reused as h2lin
    float* h1a      = (float*)carve((size_t)N_NODES * D_HID * 4);
    float* es       = (float*)carve((size_t)N_NODES * 4);         // reused layer 2
    float* edv      = (float*)carve((size_t)N_NODES * 4);         // reused layer 2

    float* out_ei    = out;                     // [2*E_TOT]
    float* out_alpha = out + 2 * (size_t)E_TOT; // [E_TOT]
    float* out_h2    = out + 3 * (size_t)E_TOT; // [N*64]

    const int eb = (E_TOT + 255) / 256;
    const int nb = (N_NODES + 3) / 4;
    const int gb = (N_NODES + 63) / 64;        // 782 GEMM tiles

    // CSR build (shared by both layers)
    hipMemsetAsync(cursor, 0, (size_t)N_NODES * 4, stream);
    k_hist_ei<<<eb, 256, 0, stream>>>(ei, cursor, out_ei);
    k_scan_a<<<SCAN_NB, SCAN_B, 0, stream>>>(cursor, blocksum);
    k_scan_b<<<1, SCAN_B, 0, stream>>>(blocksum, rowptr);
    k_scan_c<<<SCAN_NB, SCAN_B, 0, stream>>>(cursor, blocksum, rowptr);
    k_scatter<<<eb, 256, 0, stream>>>(ei, cursor, csr_eid);

    // layer 1
    k_gemm_t<D_IN><<<gb, 256, 0, stream>>>(x, W1, as1, ad1, h1, es, edv);
    k_agg<true, true><<<nb, 256, 0, stream>>>(h1, es, edv, rowptr, csr_eid, ei,
                                              b1, h1a, out_alpha);
    // layer 2 (h2lin aliases h1; es/edv reused)
    k_gemm_t<D_HID><<<gb, 256, 0, stream>>>(h1a, W2, as2, ad2, h1, es, edv);
    k_agg<false, false><<<nb, 256, 0, stream>>>(h1, es, edv, rowptr, csr_eid, ei,
                                                b2, out_h2, nullptr);
}

// Round 14
// 281.495 us; speedup vs baseline: 1.1415x; 1.1415x over previous
//
#include <hip/hip_runtime.h>
#include <math.h>

// Problem constants (from reference)
constexpr int N_NODES = 50000;
constexpr int E_EDGES = 800000;
constexpr int E_TOT   = E_EDGES + N_NODES;   // 850000 with self loops
constexpr int D_IN    = 128;
constexpr int D_HID   = 64;   // HID == OUT == 64
constexpr float NEG_SLOPE = 0.2f;

constexpr int SCAN_B  = 256;
constexpr int SCAN_NB = (N_NODES + SCAN_B - 1) / SCAN_B;   // 196

// ---------------- CSR build ----------------

// one pass over the edge list: histogram of dst + per-edge rank + emit
// edge_index-with-self-loops. rank[k] (the atomic's return value) is what
// lets k_scatter run WITHOUT atomics (round-11 profile: scatter was
// atomic-latency-bound, not write-BW-bound).
__global__ __launch_bounds__(256)
void k_hist_ei(const int* __restrict__ ei, int* __restrict__ counts,
               int* __restrict__ rank, float* __restrict__ out_ei) {
    int k = blockIdx.x * blockDim.x + threadIdx.x;
    if (k >= E_TOT) return;
    int src, dst;
    if (k < E_EDGES) { src = ei[k]; dst = ei[E_EDGES + k]; }
    else             { src = dst = k - E_EDGES; }
    out_ei[k]         = (float)src;
    out_ei[E_TOT + k] = (float)dst;
    rank[k] = atomicAdd(&counts[dst], 1);   // coalesced store, no added atomics
}

// scan phase A: per-block sums of counts
__global__ __launch_bounds__(256)
void k_scan_a(const int* __restrict__ counts, int* __restrict__ blocksum) {
    int i = blockIdx.x * SCAN_B + threadIdx.x;
    int lane = threadIdx.x & 63, wave = threadIdx.x >> 6;
    int v = (i < N_NODES) ? counts[i] : 0;
    #pragma unroll
    for (int off = 32; off; off >>= 1) v += __shfl_xor(v, off);
    __shared__ int ws[4];
    if (lane == 0) ws[wave] = v;
    __syncthreads();
    if (threadIdx.x == 0)
        blocksum[blockIdx.x] = ws[0] + ws[1] + ws[2] + ws[3];
}

// scan phase B: single small block scans the 196 block sums (exclusive, in place)
__global__ __launch_bounds__(256)
void k_scan_b(int* __restrict__ blocksum, int* __restrict__ rowptr) {
    __shared__ int s[SCAN_B];
    int t = threadIdx.x;
    int v = (t < SCAN_NB) ? blocksum[t] : 0;
    s[t] = v;
    __syncthreads();
    #pragma unroll
    for (int off = 1; off < SCAN_B; off <<= 1) {
        int u = (t >= off) ? s[t - off] : 0;
        __syncthreads();
        s[t] += u;
        __syncthreads();
    }
    if (t < SCAN_NB) blocksum[t] = s[t] - v;      // exclusive block base
    if (t == SCAN_B - 1) rowptr[N_NODES] = s[SCAN_B - 1];   // grand total == E_TOT
}

// scan phase C: in-block exclusive scan + block base -> rowptr
__global__ __launch_bounds__(256)
void k_scan_c(const int* __restrict__ counts, const int* __restrict__ blocksum,
              int* __restrict__ rowptr) {
    __shared__ int s[SCAN_B];
    int t = threadIdx.x;
    int i = blockIdx.x * SCAN_B + t;
    int v = (i < N_NODES) ? counts[i] : 0;
    s[t] = v;
    __syncthreads();
    #pragma unroll
    for (int off = 1; off < SCAN_B; off <<= 1) {
        int u = (t >= off) ? s[t - off] : 0;
        __syncthreads();
        s[t] += u;
        __syncthreads();
    }
    if (i < N_NODES) rowptr[i] = s[t] - v + blocksum[blockIdx.x];
}

// scatter, ATOMIC-FREE: pos = rowptr[dst] + rank[k]. Coalesced reads,
// read-only cached rowptr gather, one fire-and-forget random 4B store.
__global__ __launch_bounds__(256)
void k_scatter(const int* __restrict__ ei, const int* __restrict__ rank,
               const int* __restrict__ rowptr, int* __restrict__ csr_eid) {
    int k = blockIdx.x * blockDim.x + threadIdx.x;
    if (k >= E_TOT) return;
    int dst = (k < E_EDGES) ? ei[E_EDGES + k] : (k - E_EDGES);
    csr_eid[rowptr[dst] + rank[k]] = k;
}

// ---------------- dense: h = x @ W  (+ per-node attention logits) ----------------
// Register-tiled GEMM: block = 256 threads -> 64 nodes x 64 cols tile.
// W^T staged in padded LDS. Each thread owns a 4x4 register tile.

template<int K>
__global__ __launch_bounds__(256)
void k_gemm_t(const float* __restrict__ xin, const float* __restrict__ Wg,
              const float* __restrict__ a_s, const float* __restrict__ a_d,
              float* __restrict__ h, float* __restrict__ es, float* __restrict__ ed) {
    __shared__ float wt[64][K + 4];   // wt[col][k] = Wg[k][col]
    const int t = threadIdx.x;
    const int lane = t & 63, wid = t >> 6;
    for (int k = wid; k < K; k += 4)
        wt[lane][k] = Wg[k * 64 + lane];
    __syncthreads();

    const int cg = t & 15, ng = t >> 4;
    const int c0 = cg * 4;
    const int node0 = blockIdx.x * 64 + ng * 4;
    if (node0 >= N_NODES) return;    // N_NODES % 4 == 0: all-or-nothing per thread
    const float* xrow = xin + (size_t)node0 * K;

    float acc[4][4];
    #pragma unroll
    for (int n = 0; n < 4; ++n)
        #pragma unroll
        for (int i = 0; i < 4; ++i) acc[n][i] = 0.f;

    #pragma unroll 4
    for (int k = 0; k < K; k += 4) {
        float4 xv[4], wv[4];
        #pragma unroll
        for (int n = 0; n < 4; ++n) xv[n] = *(const float4*)(xrow + n * K + k);
        #pragma unroll
        for (int i = 0; i < 4; ++i) wv[i] = *(const float4*)(&wt[c0 + i][k]);
        #pragma unroll
        for (int n = 0; n < 4; ++n) {
            #pragma unroll
            for (int i = 0; i < 4; ++i) {
                acc[n][i] = fmaf(xv[n].x, wv[i].x, acc[n][i]);
                acc[n][i] = fmaf(xv[n].y, wv[i].y, acc[n][i]);
                acc[n][i] = fmaf(xv[n].z, wv[i].z, acc[n][i]);
                acc[n][i] = fmaf(xv[n].w, wv[i].w, acc[n][i]);
            }
        }
    }

    const float4 as4 = *(const float4*)(a_s + c0);
    const float4 ad4 = *(const float4*)(a_d + c0);
    #pragma unroll
    for (int n = 0; n < 4; ++n) {
        float4 hv = make_float4(acc[n][0], acc[n][1], acc[n][2], acc[n][3]);
        *(float4*)(h + (size_t)(node0 + n) * D_HID + c0) = hv;
        float vs = acc[n][0] * as4.x + acc[n][1] * as4.y
                 + acc[n][2] * as4.z + acc[n][3] * as4.w;
        float vd = acc[n][0] * ad4.x + acc[n][1] * ad4.y
                 + acc[n][2] * ad4.z + acc[n][3] * ad4.w;
        #pragma unroll
        for (int off = 8; off; off >>= 1) {   // butterfly across the 16 col-lanes
            vs += __shfl_xor(vs, off);
            vd += __shfl_xor(vd, off);
        }
        if (cg == 0) { es[node0 + n] = vs; ed[node0 + n] = vd; }
    }
}

// ---------------- sparse: segment softmax + weighted aggregation ----------------
// one wave per destination node; src derived from csr_eid via ei

template<bool RELU, bool WRITE_ALPHA>
__global__ __launch_bounds__(256)
void k_agg(const float* __restrict__ h, const float* __restrict__ es,
           const float* __restrict__ ed, const int* __restrict__ rowptr,
           const int* __restrict__ csr_eid, const int* __restrict__ ei,
           const float* __restrict__ bias, float* __restrict__ out,
           float* __restrict__ alpha_out) {
    int wave = threadIdx.x >> 6, lane = threadIdx.x & 63;
    int node = blockIdx.x * 4 + wave;
    if (node >= N_NODES) return;
    int lo  = __builtin_amdgcn_readfirstlane(rowptr[node]);
    int deg = __builtin_amdgcn_readfirstlane(rowptr[node + 1]) - lo;
    float edv = ed[node];

    if (deg <= 64) {
        // ---- fast path: lane-parallel logits, register-resident softmax ----
        int   s = 0, eid = 0;
        float e = -INFINITY;
        if (lane < deg) {
            eid = csr_eid[lo + lane];
            s   = (eid < E_EDGES) ? ei[eid] : (eid - E_EDGES);
            e = es[s] + edv;
            e = (e >= 0.f) ? e : NEG_SLOPE * e;
        }
        float m = e;
        #pragma unroll
        for (int off = 32; off; off >>= 1) m = fmaxf(m, __shfl_xor(m, off));
        float ex = (lane < deg) ? __expf(e - m) : 0.f;
        float z = ex;
        #pragma unroll
        for (int off = 32; off; off >>= 1) z += __shfl_xor(z, off);
        float inv = 1.f / z;

        // 4 independent fma/load chains for memory-level parallelism
        float a0 = 0.f, a1 = 0.f, a2 = 0.f, a3 = 0.f;
        int j = 0;
        for (; j + 4 <= deg; j += 4) {
            int   s0 = __shfl(s, j),     s1 = __shfl(s, j + 1);
            int   s2 = __shfl(s, j + 2), s3 = __shfl(s, j + 3);
            float e0 = __shfl(ex, j),     e1 = __shfl(ex, j + 1);
            float e2 = __shfl(ex, j + 2), e3 = __shfl(ex, j + 3);
            a0 = fmaf(e0, h[s0 * D_HID + lane], a0);
            a1 = fmaf(e1, h[s1 * D_HID + lane], a1);
            a2 = fmaf(e2, h[s2 * D_HID + lane], a2);
            a3 = fmaf(e3, h[s3 * D_HID + lane], a3);
        }
        for (; j < deg; ++j) {
            int   sj  = __shfl(s, j);
            float exj = __shfl(ex, j);
            a0 = fmaf(exj, h[sj * D_HID + lane], a0);
        }
        float acc = (a0 + a1) + (a2 + a3);
        float res = fmaf(acc, inv, bias[lane]);
        if (RELU) res = fmaxf(res, 0.f);
        out[node * D_HID + lane] = res;
        if (WRITE_ALPHA && lane < deg) alpha_out[eid] = ex * inv;
    } else {
        // ---- fallback: serial 3-pass (degree > 64; effectively never) ----
        int hi = lo + deg;
        float m = -INFINITY;
        for (int j = lo; j < hi; ++j) {
            int eid = csr_eid[j];
            int s   = (eid < E_EDGES) ? ei[eid] : (eid - E_EDGES);
            float e = es[s] + edv;
            e = (e >= 0.f) ? e : NEG_SLOPE * e;
            m = fmaxf(m, e);
        }
        float z = 0.f, acc = 0.f;
        for (int j = lo; j < hi; ++j) {
            int eid = csr_eid[j];
            int s   = (eid < E_EDGES) ? ei[eid] : (eid - E_EDGES);
            float e = es[s] + edv;
            e = (e >= 0.f) ? e : NEG_SLOPE * e;
            float ex = __expf(e - m);
            z += ex;
            acc = fmaf(ex, h[s * D_HID + lane], acc);
        }
        float inv = 1.f / z;
        float res = fmaf(acc, inv, bias[lane]);
        if (RELU) res = fmaxf(res, 0.f);
        out[node * D_HID + lane] = res;
        if (WRITE_ALPHA) {
            for (int j = lo + lane; j < hi; j += 64) {
                int eid = csr_eid[j];
                int s   = (eid < E_EDGES) ? ei[eid] : (eid - E_EDGES);
                float e = es[s] + edv;
                e = (e >= 0.f) ? e : NEG_SLOPE * e;
                alpha_out[eid] = __expf(e - m) * inv;
            }
        }
    }
}

// ---------------- launch ----------------

extern "C" void kernel_launch(void* const* d_in, const int* in_sizes, int n_in,
                              void* d_out, int out_size, void* d_ws, size_t ws_size,
                              hipStream_t stream) {
    const float* x    = (const float*)d_in[0];
    const int*   ei   = (const int*)d_in[1];
    const float* W1   = (const float*)d_in[2];
    const float* as1  = (const float*)d_in[3];
    const float* ad1  = (const float*)d_in[4];
    const float* b1   = (const float*)d_in[5];
    const float* W2   = (const float*)d_in[6];
    const float* as2  = (const float*)d_in[7];
    const float* ad2  = (const float*)d_in[8];
    const float* b2   = (const float*)d_in[9];
    float* out = (float*)d_out;

    // carve workspace (~34 MB)
    size_t off = 0;
    auto carve = [&](size_t bytes) -> void* {
        void* p = (char*)d_ws + off;
        off += (bytes + 255) & ~(size_t)255;
        return p;
    };
    int*   counts   = (int*)carve((size_t)N_NODES * 4);
    int*   rowptr   = (int*)carve((size_t)(N_NODES + 1) * 4);
    int*   blocksum = (int*)carve((size_t)SCAN_NB * 4);
    int*   rank     = (int*)carve((size_t)E_TOT * 4);
    int*   csr_eid  = (int*)carve((size_t)E_TOT * 4);
    float* h1       = (float*)carve((size_t)N_NODES * D_HID * 4); // reused as h2lin
    float* h1a      = (float*)carve((size_t)N_NODES * D_HID * 4);
    float* es       = (float*)carve((size_t)N_NODES * 4);         // reused layer 2
    float* edv      = (float*)carve((size_t)N_NODES * 4);         // reused layer 2

    float* out_ei    = out;                     // [2*E_TOT]
    float* out_alpha = out + 2 * (size_t)E_TOT; // [E_TOT]
    float* out_h2    = out + 3 * (size_t)E_TOT; // [N*64]

    const int eb = (E_TOT + 255) / 256;
    const int nb = (N_NODES + 3) / 4;
    const int gb = (N_NODES + 63) / 64;        // 782 GEMM tiles

    // CSR build (shared by both layers)
    hipMemsetAsync(counts, 0, (size_t)N_NODES * 4, stream);
    k_hist_ei<<<eb, 256, 0, stream>>>(ei, counts, rank, out_ei);
    k_scan_a<<<SCAN_NB, SCAN_B, 0, stream>>>(counts, blocksum);
    k_scan_b<<<1, SCAN_B, 0, stream>>>(blocksum, rowptr);
    k_scan_c<<<SCAN_NB, SCAN_B, 0, stream>>>(counts, blocksum, rowptr);
    k_scatter<<<eb, 256, 0, stream>>>(ei, rank, rowptr, csr_eid);

    // layer 1
    k_gemm_t<D_IN><<<gb, 256, 0, stream>>>(x, W1, as1, ad1, h1, es, edv);
    k_agg<true, true><<<nb, 256, 0, stream>>>(h1, es, edv, rowptr, csr_eid, ei,
                                              b1, h1a, out_alpha);
    // layer 2 (h2lin aliases h1; es/edv reused)
    k_gemm_t<D_HID><<<gb, 256, 0, stream>>>(h1a, W2, as2, ad2, h1, es, edv);
    k_agg<false, false><<<nb, 256, 0, stream>>>(h1, es, edv, rowptr, csr_eid, ei,
                                                b2, out_h2, nullptr);
}

// Round 15
// 279.042 us; speedup vs baseline: 1.1515x; 1.0088x over previous
//
#include <hip/hip_runtime.h>
#include <math.h>

// Problem constants (from reference)
constexpr int N_NODES = 50000;
constexpr int E_EDGES = 800000;
constexpr int E_TOT   = E_EDGES + N_NODES;   // 850000 with self loops
constexpr int D_IN    = 128;
constexpr int D_HID   = 64;   // HID == OUT == 64
constexpr float NEG_SLOPE = 0.2f;

constexpr int SCAN_B  = 256;
constexpr int SCAN_NB = (N_NODES + SCAN_B - 1) / SCAN_B;   // 196

// ---------------- CSR build ----------------

// one pass over the edge list, 2 edges/thread: histogram + rank + emit ei.
// E_EDGES is even, so a pair never straddles the edge/self-loop boundary.
__global__ __launch_bounds__(256)
void k_hist_ei(const int* __restrict__ ei, int* __restrict__ counts,
               int* __restrict__ rank, float* __restrict__ out_ei) {
    int p = blockIdx.x * blockDim.x + threadIdx.x;
    int k = p * 2;
    if (k >= E_TOT) return;
    int s0, d0, s1, d1;
    if (k < E_EDGES) {
        int2 sv = *(const int2*)(ei + k);
        int2 dv = *(const int2*)(ei + E_EDGES + k);
        s0 = sv.x; s1 = sv.y; d0 = dv.x; d1 = dv.y;
    } else {
        s0 = d0 = k - E_EDGES;
        s1 = d1 = k + 1 - E_EDGES;
    }
    *(float2*)(out_ei + k)         = make_float2((float)s0, (float)s1);
    *(float2*)(out_ei + E_TOT + k) = make_float2((float)d0, (float)d1);
    int r0 = atomicAdd(&counts[d0], 1);
    int r1 = atomicAdd(&counts[d1], 1);
    *(int2*)(rank + k) = make_int2(r0, r1);
}

// scan phase A: per-block sums of counts
__global__ __launch_bounds__(256)
void k_scan_a(const int* __restrict__ counts, int* __restrict__ blocksum) {
    int i = blockIdx.x * SCAN_B + threadIdx.x;
    int lane = threadIdx.x & 63, wave = threadIdx.x >> 6;
    int v = (i < N_NODES) ? counts[i] : 0;
    #pragma unroll
    for (int off = 32; off; off >>= 1) v += __shfl_xor(v, off);
    __shared__ int ws[4];
    if (lane == 0) ws[wave] = v;
    __syncthreads();
    if (threadIdx.x == 0)
        blocksum[blockIdx.x] = ws[0] + ws[1] + ws[2] + ws[3];
}

// scan phase B: single small block scans the 196 block sums (exclusive, in place)
__global__ __launch_bounds__(256)
void k_scan_b(int* __restrict__ blocksum, int* __restrict__ rowptr) {
    __shared__ int s[SCAN_B];
    int t = threadIdx.x;
    int v = (t < SCAN_NB) ? blocksum[t] : 0;
    s[t] = v;
    __syncthreads();
    #pragma unroll
    for (int off = 1; off < SCAN_B; off <<= 1) {
        int u = (t >= off) ? s[t - off] : 0;
        __syncthreads();
        s[t] += u;
        __syncthreads();
    }
    if (t < SCAN_NB) blocksum[t] = s[t] - v;      // exclusive block base
    if (t == SCAN_B - 1) rowptr[N_NODES] = s[SCAN_B - 1];   // grand total == E_TOT
}

// scan phase C: in-block exclusive scan + block base -> rowptr
__global__ __launch_bounds__(256)
void k_scan_c(const int* __restrict__ counts, const int* __restrict__ blocksum,
              int* __restrict__ rowptr) {
    __shared__ int s[SCAN_B];
    int t = threadIdx.x;
    int i = blockIdx.x * SCAN_B + t;
    int v = (i < N_NODES) ? counts[i] : 0;
    s[t] = v;
    __syncthreads();
    #pragma unroll
    for (int off = 1; off < SCAN_B; off <<= 1) {
        int u = (t >= off) ? s[t - off] : 0;
        __syncthreads();
        s[t] += u;
        __syncthreads();
    }
    if (i < N_NODES) rowptr[i] = s[t] - v + blocksum[blockIdx.x];
}

// scatter, ATOMIC-FREE, 2 edges/thread: pos = rowptr[dst] + rank[k].
__global__ __launch_bounds__(256)
void k_scatter(const int* __restrict__ ei, const int* __restrict__ rank,
               const int* __restrict__ rowptr, int* __restrict__ csr_eid) {
    int p = blockIdx.x * blockDim.x + threadIdx.x;
    int k = p * 2;
    if (k >= E_TOT) return;
    int d0, d1;
    if (k < E_EDGES) {
        int2 dv = *(const int2*)(ei + E_EDGES + k);
        d0 = dv.x; d1 = dv.y;
    } else {
        d0 = k - E_EDGES;
        d1 = k + 1 - E_EDGES;
    }
    int2 rv = *(const int2*)(rank + k);
    csr_eid[rowptr[d0] + rv.x] = k;
    csr_eid[rowptr[d1] + rv.y] = k + 1;
}

// ---------------- dense: h = x @ W  (+ per-node attention logits) ----------------
// Register-tiled GEMM: block = 256 threads -> 64 nodes x 64 cols tile.
// W^T staged in padded LDS. Each thread owns a 4x4 register tile.

template<int K>
__global__ __launch_bounds__(256)
void k_gemm_t(const float* __restrict__ xin, const float* __restrict__ Wg,
              const float* __restrict__ a_s, const float* __restrict__ a_d,
              float* __restrict__ h, float* __restrict__ es, float* __restrict__ ed) {
    __shared__ float wt[64][K + 4];   // wt[col][k] = Wg[k][col]
    const int t = threadIdx.x;
    const int lane = t & 63, wid = t >> 6;
    for (int k = wid; k < K; k += 4)
        wt[lane][k] = Wg[k * 64 + lane];
    __syncthreads();

    const int cg = t & 15, ng = t >> 4;
    const int c0 = cg * 4;
    const int node0 = blockIdx.x * 64 + ng * 4;
    if (node0 >= N_NODES) return;    // N_NODES % 4 == 0: all-or-nothing per thread
    const float* xrow = xin + (size_t)node0 * K;

    float acc[4][4];
    #pragma unroll
    for (int n = 0; n < 4; ++n)
        #pragma unroll
        for (int i = 0; i < 4; ++i) acc[n][i] = 0.f;

    #pragma unroll 4
    for (int k = 0; k < K; k += 4) {
        float4 xv[4], wv[4];
        #pragma unroll
        for (int n = 0; n < 4; ++n) xv[n] = *(const float4*)(xrow + n * K + k);
        #pragma unroll
        for (int i = 0; i < 4; ++i) wv[i] = *(const float4*)(&wt[c0 + i][k]);
        #pragma unroll
        for (int n = 0; n < 4; ++n) {
            #pragma unroll
            for (int i = 0; i < 4; ++i) {
                acc[n][i] = fmaf(xv[n].x, wv[i].x, acc[n][i]);
                acc[n][i] = fmaf(xv[n].y, wv[i].y, acc[n][i]);
                acc[n][i] = fmaf(xv[n].z, wv[i].z, acc[n][i]);
                acc[n][i] = fmaf(xv[n].w, wv[i].w, acc[n][i]);
            }
        }
    }

    const float4 as4 = *(const float4*)(a_s + c0);
    const float4 ad4 = *(const float4*)(a_d + c0);
    #pragma unroll
    for (int n = 0; n < 4; ++n) {
        float4 hv = make_float4(acc[n][0], acc[n][1], acc[n][2], acc[n][3]);
        *(float4*)(h + (size_t)(node0 + n) * D_HID + c0) = hv;
        float vs = acc[n][0] * as4.x + acc[n][1] * as4.y
                 + acc[n][2] * as4.z + acc[n][3] * as4.w;
        float vd = acc[n][0] * ad4.x + acc[n][1] * ad4.y
                 + acc[n][2] * ad4.z + acc[n][3] * ad4.w;
        #pragma unroll
        for (int off = 8; off; off >>= 1) {   // butterfly across the 16 col-lanes
            vs += __shfl_xor(vs, off);
            vd += __shfl_xor(vd, off);
        }
        if (cg == 0) { es[node0 + n] = vs; ed[node0 + n] = vd; }
    }
}

// ---------------- sparse: segment softmax + weighted aggregation ----------------
// one wave per destination node; src derived from csr_eid via ei.
// Aggregate loop: 8 independent load/fma chains (round-14 profile: k_agg is
// latency-exposed — VALUBusy 29%, 3.35 TB/s of ~6.3 achievable — not BW-bound).

template<bool RELU, bool WRITE_ALPHA>
__global__ __launch_bounds__(256)
void k_agg(const float* __restrict__ h, const float* __restrict__ es,
           const float* __restrict__ ed, const int* __restrict__ rowptr,
           const int* __restrict__ csr_eid, const int* __restrict__ ei,
           const float* __restrict__ bias, float* __restrict__ out,
           float* __restrict__ alpha_out) {
    int wave = threadIdx.x >> 6, lane = threadIdx.x & 63;
    int node = blockIdx.x * 4 + wave;
    if (node >= N_NODES) return;
    int lo  = __builtin_amdgcn_readfirstlane(rowptr[node]);
    int deg = __builtin_amdgcn_readfirstlane(rowptr[node + 1]) - lo;
    float edv = ed[node];

    if (deg <= 64) {
        // ---- fast path: lane-parallel logits, register-resident softmax ----
        int   s = 0, eid = 0;
        float e = -INFINITY;
        if (lane < deg) {
            eid = csr_eid[lo + lane];
            s   = (eid < E_EDGES) ? ei[eid] : (eid - E_EDGES);
            e = es[s] + edv;
            e = (e >= 0.f) ? e : NEG_SLOPE * e;
        }
        float m = e;
        #pragma unroll
        for (int off = 32; off; off >>= 1) m = fmaxf(m, __shfl_xor(m, off));
        float ex = (lane < deg) ? __expf(e - m) : 0.f;
        float z = ex;
        #pragma unroll
        for (int off = 32; off; off >>= 1) z += __shfl_xor(z, off);
        float inv = 1.f / z;

        // 8 independent fma/load chains for memory-level parallelism
        float a0 = 0.f, a1 = 0.f, a2 = 0.f, a3 = 0.f;
        float a4 = 0.f, a5 = 0.f, a6 = 0.f, a7 = 0.f;
        int j = 0;
        for (; j + 8 <= deg; j += 8) {
            int   s0 = __shfl(s, j),     s1 = __shfl(s, j + 1);
            int   s2 = __shfl(s, j + 2), s3 = __shfl(s, j + 3);
            int   s4 = __shfl(s, j + 4), s5 = __shfl(s, j + 5);
            int   s6 = __shfl(s, j + 6), s7 = __shfl(s, j + 7);
            float e0 = __shfl(ex, j),     e1 = __shfl(ex, j + 1);
            float e2 = __shfl(ex, j + 2), e3 = __shfl(ex, j + 3);
            float e4 = __shfl(ex, j + 4), e5 = __shfl(ex, j + 5);
            float e6 = __shfl(ex, j + 6), e7 = __shfl(ex, j + 7);
            a0 = fmaf(e0, h[s0 * D_HID + lane], a0);
            a1 = fmaf(e1, h[s1 * D_HID + lane], a1);
            a2 = fmaf(e2, h[s2 * D_HID + lane], a2);
            a3 = fmaf(e3, h[s3 * D_HID + lane], a3);
            a4 = fmaf(e4, h[s4 * D_HID + lane], a4);
            a5 = fmaf(e5, h[s5 * D_HID + lane], a5);
            a6 = fmaf(e6, h[s6 * D_HID + lane], a6);
            a7 = fmaf(e7, h[s7 * D_HID + lane], a7);
        }
        for (; j + 4 <= deg; j += 4) {
            int   s0 = __shfl(s, j),     s1 = __shfl(s, j + 1);
            int   s2 = __shfl(s, j + 2), s3 = __shfl(s, j + 3);
            float e0 = __shfl(ex, j),     e1 = __shfl(ex, j + 1);
            float e2 = __shfl(ex, j + 2), e3 = __shfl(ex, j + 3);
            a0 = fmaf(e0, h[s0 * D_HID + lane], a0);
            a1 = fmaf(e1, h[s1 * D_HID + lane], a1);
            a2 = fmaf(e2, h[s2 * D_HID + lane], a2);
            a3 = fmaf(e3, h[s3 * D_HID + lane], a3);
        }
        for (; j < deg; ++j) {
            int   sj  = __shfl(s, j);
            float exj = __shfl(ex, j);
            a0 = fmaf(exj, h[sj * D_HID + lane], a0);
        }
        float acc = ((a0 + a1) + (a2 + a3)) + ((a4 + a5) + (a6 + a7));
        float res = fmaf(acc, inv, bias[lane]);
        if (RELU) res = fmaxf(res, 0.f);
        out[node * D_HID + lane] = res;
        if (WRITE_ALPHA && lane < deg) alpha_out[eid] = ex * inv;
    } else {
        // ---- fallback: serial 3-pass (degree > 64; effectively never) ----
        int hi = lo + deg;
        float m = -INFINITY;
        for (int j = lo; j < hi; ++j) {
            int eid = csr_eid[j];
            int s   = (eid < E_EDGES) ? ei[eid] : (eid - E_EDGES);
            float e = es[s] + edv;
            e = (e >= 0.f) ? e : NEG_SLOPE * e;
            m = fmaxf(m, e);
        }
        float z = 0.f, acc = 0.f;
        for (int j = lo; j < hi; ++j) {
            int eid = csr_eid[j];
            int s   = (eid < E_EDGES) ? ei[eid] : (eid - E_EDGES);
            float e = es[s] + edv;
            e = (e >= 0.f) ? e : NEG_SLOPE * e;
            float ex = __expf(e - m);
            z += ex;
            acc = fmaf(ex, h[s * D_HID + lane], acc);
        }
        float inv = 1.f / z;
        float res = fmaf(acc, inv, bias[lane]);
        if (RELU) res = fmaxf(res, 0.f);
        out[node * D_HID + lane] = res;
        if (WRITE_ALPHA) {
            for (int j = lo + lane; j < hi; j += 64) {
                int eid = csr_eid[j];
                int s   = (eid < E_EDGES) ? ei[eid] : (eid - E_EDGES);
                float e = es[s] + edv;
                e = (e >= 0.f) ? e : NEG_SLOPE * e;
                alpha_out[eid] = __expf(e - m) * inv;
            }
        }
    }
}

// ---------------- launch ----------------

extern "C" void kernel_launch(void* const* d_in, const int* in_sizes, int n_in,
                              void* d_out, int out_size, void* d_ws, size_t ws_size,
                              hipStream_t stream) {
    const float* x    = (const float*)d_in[0];
    const int*   ei   = (const int*)d_in[1];
    const float* W1   = (const float*)d_in[2];
    const float* as1  = (const float*)d_in[3];
    const float* ad1  = (const float*)d_in[4];
    const float* b1   = (const float*)d_in[5];
    const float* W2   = (const float*)d_in[6];
    const float* as2  = (const float*)d_in[7];
    const float* ad2  = (const float*)d_in[8];
    const float* b2   = (const float*)d_in[9];
    float* out = (float*)d_out;

    // carve workspace (~34 MB)
    size_t off = 0;
    auto carve = [&](size_t bytes) -> void* {
        void* p = (char*)d_ws + off;
        off += (bytes + 255) & ~(size_t)255;
        return p;
    };
    int*   counts   = (int*)carve((size_t)N_NODES * 4);
    int*   rowptr   = (int*)carve((size_t)(N_NODES + 1) * 4);
    int*   blocksum = (int*)carve((size_t)SCAN_NB * 4);
    int*   rank     = (int*)carve((size_t)E_TOT * 4);
    int*   csr_eid  = (int*)carve((size_t)E_TOT * 4);
    float* h1       = (float*)carve((size_t)N_NODES * D_HID * 4); // reused as h2lin
    float* h1a      = (float*)carve((size_t)N_NODES * D_HID * 4);
    float* es       = (float*)carve((size_t)N_NODES * 4);         // reused layer 2
    float* edv      = (float*)carve((size_t)N_NODES * 4);         // reused layer 2

    float* out_ei    = out;                     // [2*E_TOT]
    float* out_alpha = out + 2 * (size_t)E_TOT; // [E_TOT]
    float* out_h2    = out + 3 * (size_t)E_TOT; // [N*64]

    const int eb2 = (E_TOT / 2 + 255) / 256;   // 2 edges/thread
    const int nb  = (N_NODES + 3) / 4;
    const int gb  = (N_NODES + 63) / 64;       // 782 GEMM tiles

    // CSR build (shared by both layers)
    hipMemsetAsync(counts, 0, (size_t)N_NODES * 4, stream);
    k_hist_ei<<<eb2, 256, 0, stream>>>(ei, counts, rank, out_ei);
    k_scan_a<<<SCAN_NB, SCAN_B, 0, stream>>>(counts, blocksum);
    k_scan_b<<<1, SCAN_B, 0, stream>>>(blocksum, rowptr);
    k_scan_c<<<SCAN_NB, SCAN_B, 0, stream>>>(counts, blocksum, rowptr);
    k_scatter<<<eb2, 256, 0, stream>>>(ei, rank, rowptr, csr_eid);

    // layer 1
    k_gemm_t<D_IN><<<gb, 256, 0, stream>>>(x, W1, as1, ad1, h1, es, edv);
    k_agg<true, true><<<nb, 256, 0, stream>>>(h1, es, edv, rowptr, csr_eid, ei,
                                              b1, h1a, out_alpha);
    // layer 2 (h2lin aliases h1; es/edv reused)
    k_gemm_t<D_HID><<<gb, 256, 0, stream>>>(h1a, W2, as2, ad2, h1, es, edv);
    k_agg<false, false><<<nb, 256, 0, stream>>>(h1, es, edv, rowptr, csr_eid, ei,
                                                b2, out_h2, nullptr);
}

// Round 16
// 261.202 us; speedup vs baseline: 1.2301x; 1.0683x over previous
//
#include <hip/hip_runtime.h>
#include <math.h>

// Problem constants (from reference)
constexpr int N_NODES = 50000;
constexpr int E_EDGES = 800000;
constexpr int E_TOT   = E_EDGES + N_NODES;   // 850000 with self loops
constexpr int D_IN    = 128;
constexpr int D_HID   = 64;   // HID == OUT == 64
constexpr float NEG_SLOPE = 0.2f;

constexpr int SCAN_B  = 256;
constexpr int SCAN_NB = (N_NODES + SCAN_B - 1) / SCAN_B;   // 196

// bf16 pack (RNE) / unpack — h is stored bf16 for the k_agg gather path:
// round-15 profile shows k_agg at a random-gather traffic floor
// (FETCH 133MB ~= 8 XCDs x full h refetch); halving row bytes halves it.
__device__ __forceinline__ unsigned short f2bf(float f) {
    unsigned int u = __float_as_uint(f);
    u += 0x7FFFu + ((u >> 16) & 1u);
    return (unsigned short)(u >> 16);
}
__device__ __forceinline__ float bf2f(unsigned short b) {
    return __uint_as_float(((unsigned int)b) << 16);
}

// ---------------- CSR build ----------------

// one pass over the edge list, 2 edges/thread: histogram + rank + emit ei.
// E_EDGES is even, so a pair never straddles the edge/self-loop boundary.
__global__ __launch_bounds__(256)
void k_hist_ei(const int* __restrict__ ei, int* __restrict__ counts,
               int* __restrict__ rank, float* __restrict__ out_ei) {
    int p = blockIdx.x * blockDim.x + threadIdx.x;
    int k = p * 2;
    if (k >= E_TOT) return;
    int s0, d0, s1, d1;
    if (k < E_EDGES) {
        int2 sv = *(const int2*)(ei + k);
        int2 dv = *(const int2*)(ei + E_EDGES + k);
        s0 = sv.x; s1 = sv.y; d0 = dv.x; d1 = dv.y;
    } else {
        s0 = d0 = k - E_EDGES;
        s1 = d1 = k + 1 - E_EDGES;
    }
    *(float2*)(out_ei + k)         = make_float2((float)s0, (float)s1);
    *(float2*)(out_ei + E_TOT + k) = make_float2((float)d0, (float)d1);
    int r0 = atomicAdd(&counts[d0], 1);
    int r1 = atomicAdd(&counts[d1], 1);
    *(int2*)(rank + k) = make_int2(r0, r1);
}

// scan phase A: per-block sums of counts
__global__ __launch_bounds__(256)
void k_scan_a(const int* __restrict__ counts, int* __restrict__ blocksum) {
    int i = blockIdx.x * SCAN_B + threadIdx.x;
    int lane = threadIdx.x & 63, wave = threadIdx.x >> 6;
    int v = (i < N_NODES) ? counts[i] : 0;
    #pragma unroll
    for (int off = 32; off; off >>= 1) v += __shfl_xor(v, off);
    __shared__ int ws[4];
    if (lane == 0) ws[wave] = v;
    __syncthreads();
    if (threadIdx.x == 0)
        blocksum[blockIdx.x] = ws[0] + ws[1] + ws[2] + ws[3];
}

// scan phase B: single small block scans the 196 block sums (exclusive, in place)
__global__ __launch_bounds__(256)
void k_scan_b(int* __restrict__ blocksum, int* __restrict__ rowptr) {
    __shared__ int s[SCAN_B];
    int t = threadIdx.x;
    int v = (t < SCAN_NB) ? blocksum[t] : 0;
    s[t] = v;
    __syncthreads();
    #pragma unroll
    for (int off = 1; off < SCAN_B; off <<= 1) {
        int u = (t >= off) ? s[t - off] : 0;
        __syncthreads();
        s[t] += u;
        __syncthreads();
    }
    if (t < SCAN_NB) blocksum[t] = s[t] - v;      // exclusive block base
    if (t == SCAN_B - 1) rowptr[N_NODES] = s[SCAN_B - 1];   // grand total == E_TOT
}

// scan phase C: in-block exclusive scan + block base -> rowptr
__global__ __launch_bounds__(256)
void k_scan_c(const int* __restrict__ counts, const int* __restrict__ blocksum,
              int* __restrict__ rowptr) {
    __shared__ int s[SCAN_B];
    int t = threadIdx.x;
    int i = blockIdx.x * SCAN_B + t;
    int v = (i < N_NODES) ? counts[i] : 0;
    s[t] = v;
    __syncthreads();
    #pragma unroll
    for (int off = 1; off < SCAN_B; off <<= 1) {
        int u = (t >= off) ? s[t - off] : 0;
        __syncthreads();
        s[t] += u;
        __syncthreads();
    }
    if (i < N_NODES) rowptr[i] = s[t] - v + blocksum[blockIdx.x];
}

// scatter, ATOMIC-FREE, 2 edges/thread: pos = rowptr[dst] + rank[k].
__global__ __launch_bounds__(256)
void k_scatter(const int* __restrict__ ei, const int* __restrict__ rank,
               const int* __restrict__ rowptr, int* __restrict__ csr_eid) {
    int p = blockIdx.x * blockDim.x + threadIdx.x;
    int k = p * 2;
    if (k >= E_TOT) return;
    int d0, d1;
    if (k < E_EDGES) {
        int2 dv = *(const int2*)(ei + E_EDGES + k);
        d0 = dv.x; d1 = dv.y;
    } else {
        d0 = k - E_EDGES;
        d1 = k + 1 - E_EDGES;
    }
    int2 rv = *(const int2*)(rank + k);
    csr_eid[rowptr[d0] + rv.x] = k;
    csr_eid[rowptr[d1] + rv.y] = k + 1;
}

// ---------------- dense: h = x @ W  (+ per-node attention logits) ----------------
// Register-tiled GEMM -> bf16 h (gather operand) + fp32 es/ed (from registers,
// so attention logits & alpha stay fp32-exact vs the fp32 reference path).

template<int K>
__global__ __launch_bounds__(256)
void k_gemm_t(const float* __restrict__ xin, const float* __restrict__ Wg,
              const float* __restrict__ a_s, const float* __restrict__ a_d,
              unsigned short* __restrict__ hb, float* __restrict__ es,
              float* __restrict__ ed) {
    __shared__ float wt[64][K + 4];   // wt[col][k] = Wg[k][col]
    const int t = threadIdx.x;
    const int lane = t & 63, wid = t >> 6;
    for (int k = wid; k < K; k += 4)
        wt[lane][k] = Wg[k * 64 + lane];
    __syncthreads();

    const int cg = t & 15, ng = t >> 4;
    const int c0 = cg * 4;
    const int node0 = blockIdx.x * 64 + ng * 4;
    if (node0 >= N_NODES) return;    // N_NODES % 4 == 0: all-or-nothing per thread
    const float* xrow = xin + (size_t)node0 * K;

    float acc[4][4];
    #pragma unroll
    for (int n = 0; n < 4; ++n)
        #pragma unroll
        for (int i = 0; i < 4; ++i) acc[n][i] = 0.f;

    #pragma unroll 4
    for (int k = 0; k < K; k += 4) {
        float4 xv[4], wv[4];
        #pragma unroll
        for (int n = 0; n < 4; ++n) xv[n] = *(const float4*)(xrow + n * K + k);
        #pragma unroll
        for (int i = 0; i < 4; ++i) wv[i] = *(const float4*)(&wt[c0 + i][k]);
        #pragma unroll
        for (int n = 0; n < 4; ++n) {
            #pragma unroll
            for (int i = 0; i < 4; ++i) {
                acc[n][i] = fmaf(xv[n].x, wv[i].x, acc[n][i]);
                acc[n][i] = fmaf(xv[n].y, wv[i].y, acc[n][i]);
                acc[n][i] = fmaf(xv[n].z, wv[i].z, acc[n][i]);
                acc[n][i] = fmaf(xv[n].w, wv[i].w, acc[n][i]);
            }
        }
    }

    const float4 as4 = *(const float4*)(a_s + c0);
    const float4 ad4 = *(const float4*)(a_d + c0);
    #pragma unroll
    for (int n = 0; n < 4; ++n) {
        ushort4 hv4;
        hv4.x = f2bf(acc[n][0]); hv4.y = f2bf(acc[n][1]);
        hv4.z = f2bf(acc[n][2]); hv4.w = f2bf(acc[n][3]);
        *(ushort4*)(hb + (size_t)(node0 + n) * D_HID + c0) = hv4;
        float vs = acc[n][0] * as4.x + acc[n][1] * as4.y
                 + acc[n][2] * as4.z + acc[n][3] * as4.w;
        float vd = acc[n][0] * ad4.x + acc[n][1] * ad4.y
                 + acc[n][2] * ad4.z + acc[n][3] * ad4.w;
        #pragma unroll
        for (int off = 8; off; off >>= 1) {   // butterfly across the 16 col-lanes
            vs += __shfl_xor(vs, off);
            vd += __shfl_xor(vd, off);
        }
        if (cg == 0) { es[node0 + n] = vs; ed[node0 + n] = vd; }
    }
}

// ---------------- sparse: segment softmax + weighted aggregation ----------------
// one wave per destination node; src derived from csr_eid via ei.
// h gathered as bf16 (128B/row = 2 lines); alpha math stays fp32.

template<bool RELU, bool WRITE_ALPHA>
__global__ __launch_bounds__(256)
void k_agg(const unsigned short* __restrict__ hb, const float* __restrict__ es,
           const float* __restrict__ ed, const int* __restrict__ rowptr,
           const int* __restrict__ csr_eid, const int* __restrict__ ei,
           const float* __restrict__ bias, float* __restrict__ out,
           float* __restrict__ alpha_out) {
    int wave = threadIdx.x >> 6, lane = threadIdx.x & 63;
    int node = blockIdx.x * 4 + wave;
    if (node >= N_NODES) return;
    int lo  = __builtin_amdgcn_readfirstlane(rowptr[node]);
    int deg = __builtin_amdgcn_readfirstlane(rowptr[node + 1]) - lo;
    float edv = ed[node];

    if (deg <= 64) {
        // ---- fast path: lane-parallel logits, register-resident softmax ----
        int   s = 0, eid = 0;
        float e = -INFINITY;
        if (lane < deg) {
            eid = csr_eid[lo + lane];
            s   = (eid < E_EDGES) ? ei[eid] : (eid - E_EDGES);
            e = es[s] + edv;
            e = (e >= 0.f) ? e : NEG_SLOPE * e;
        }
        float m = e;
        #pragma unroll
        for (int off = 32; off; off >>= 1) m = fmaxf(m, __shfl_xor(m, off));
        float ex = (lane < deg) ? __expf(e - m) : 0.f;
        float z = ex;
        #pragma unroll
        for (int off = 32; off; off >>= 1) z += __shfl_xor(z, off);
        float inv = 1.f / z;

        // 8 independent load/fma chains
        float a0 = 0.f, a1 = 0.f, a2 = 0.f, a3 = 0.f;
        float a4 = 0.f, a5 = 0.f, a6 = 0.f, a7 = 0.f;
        int j = 0;
        for (; j + 8 <= deg; j += 8) {
            int   s0 = __shfl(s, j),     s1 = __shfl(s, j + 1);
            int   s2 = __shfl(s, j + 2), s3 = __shfl(s, j + 3);
            int   s4 = __shfl(s, j + 4), s5 = __shfl(s, j + 5);
            int   s6 = __shfl(s, j + 6), s7 = __shfl(s, j + 7);
            float e0 = __shfl(ex, j),     e1 = __shfl(ex, j + 1);
            float e2 = __shfl(ex, j + 2), e3 = __shfl(ex, j + 3);
            float e4 = __shfl(ex, j + 4), e5 = __shfl(ex, j + 5);
            float e6 = __shfl(ex, j + 6), e7 = __shfl(ex, j + 7);
            a0 = fmaf(e0, bf2f(hb[s0 * D_HID + lane]), a0);
            a1 = fmaf(e1, bf2f(hb[s1 * D_HID + lane]), a1);
            a2 = fmaf(e2, bf2f(hb[s2 * D_HID + lane]), a2);
            a3 = fmaf(e3, bf2f(hb[s3 * D_HID + lane]), a3);
            a4 = fmaf(e4, bf2f(hb[s4 * D_HID + lane]), a4);
            a5 = fmaf(e5, bf2f(hb[s5 * D_HID + lane]), a5);
            a6 = fmaf(e6, bf2f(hb[s6 * D_HID + lane]), a6);
            a7 = fmaf(e7, bf2f(hb[s7 * D_HID + lane]), a7);
        }
        for (; j + 4 <= deg; j += 4) {
            int   s0 = __shfl(s, j),     s1 = __shfl(s, j + 1);
            int   s2 = __shfl(s, j + 2), s3 = __shfl(s, j + 3);
            float e0 = __shfl(ex, j),     e1 = __shfl(ex, j + 1);
            float e2 = __shfl(ex, j + 2), e3 = __shfl(ex, j + 3);
            a0 = fmaf(e0, bf2f(hb[s0 * D_HID + lane]), a0);
            a1 = fmaf(e1, bf2f(hb[s1 * D_HID + lane]), a1);
            a2 = fmaf(e2, bf2f(hb[s2 * D_HID + lane]), a2);
            a3 = fmaf(e3, bf2f(hb[s3 * D_HID + lane]), a3);
        }
        for (; j < deg; ++j) {
            int   sj  = __shfl(s, j);
            float exj = __shfl(ex, j);
            a0 = fmaf(exj, bf2f(hb[sj * D_HID + lane]), a0);
        }
        float acc = ((a0 + a1) + (a2 + a3)) + ((a4 + a5) + (a6 + a7));
        float res = fmaf(acc, inv, bias[lane]);
        if (RELU) res = fmaxf(res, 0.f);
        out[node * D_HID + lane] = res;
        if (WRITE_ALPHA && lane < deg) alpha_out[eid] = ex * inv;
    } else {
        // ---- fallback: serial 3-pass (degree > 64; effectively never) ----
        int hi = lo + deg;
        float m = -INFINITY;
        for (int j = lo; j < hi; ++j) {
            int eid = csr_eid[j];
            int s   = (eid < E_EDGES) ? ei[eid] : (eid - E_EDGES);
            float e = es[s] + edv;
            e = (e >= 0.f) ? e : NEG_SLOPE * e;
            m = fmaxf(m, e);
        }
        float z = 0.f, acc = 0.f;
        for (int j = lo; j < hi; ++j) {
            int eid = csr_eid[j];
            int s   = (eid < E_EDGES) ? ei[eid] : (eid - E_EDGES);
            float e = es[s] + edv;
            e = (e >= 0.f) ? e : NEG_SLOPE * e;
            float ex = __expf(e - m);
            z += ex;
            acc = fmaf(ex, bf2f(hb[s * D_HID + lane]), acc);
        }
        float inv = 1.f / z;
        float res = fmaf(acc, inv, bias[lane]);
        if (RELU) res = fmaxf(res, 0.f);
        out[node * D_HID + lane] = res;
        if (WRITE_ALPHA) {
            for (int j = lo + lane; j < hi; j += 64) {
                int eid = csr_eid[j];
                int s   = (eid < E_EDGES) ? ei[eid] : (eid - E_EDGES);
                float e = es[s] + edv;
                e = (e >= 0.f) ? e : NEG_SLOPE * e;
                alpha_out[eid] = __expf(e - m) * inv;
            }
        }
    }
}

// ---------------- launch ----------------

extern "C" void kernel_launch(void* const* d_in, const int* in_sizes, int n_in,
                              void* d_out, int out_size, void* d_ws, size_t ws_size,
                              hipStream_t stream) {
    const float* x    = (const float*)d_in[0];
    const int*   ei   = (const int*)d_in[1];
    const float* W1   = (const float*)d_in[2];
    const float* as1  = (const float*)d_in[3];
    const float* ad1  = (const float*)d_in[4];
    const float* b1   = (const float*)d_in[5];
    const float* W2   = (const float*)d_in[6];
    const float* as2  = (const float*)d_in[7];
    const float* ad2  = (const float*)d_in[8];
    const float* b2   = (const float*)d_in[9];
    float* out = (float*)d_out;

    // carve workspace (~27 MB)
    size_t off = 0;
    auto carve = [&](size_t bytes) -> void* {
        void* p = (char*)d_ws + off;
        off += (bytes + 255) & ~(size_t)255;
        return p;
    };
    int*            counts   = (int*)carve((size_t)N_NODES * 4);
    int*            rowptr   = (int*)carve((size_t)(N_NODES + 1) * 4);
    int*            blocksum = (int*)carve((size_t)SCAN_NB * 4);
    int*            rank     = (int*)carve((size_t)E_TOT * 4);
    int*            csr_eid  = (int*)carve((size_t)E_TOT * 4);
    unsigned short* hb       = (unsigned short*)carve((size_t)N_NODES * D_HID * 2);
    float*          h1a      = (float*)carve((size_t)N_NODES * D_HID * 4);
    float*          es       = (float*)carve((size_t)N_NODES * 4);
    float*          edv      = (float*)carve((size_t)N_NODES * 4);

    float* out_ei    = out;                     // [2*E_TOT]
    float* out_alpha = out + 2 * (size_t)E_TOT; // [E_TOT]
    float* out_h2    = out + 3 * (size_t)E_TOT; // [N*64]

    const int eb2 = (E_TOT / 2 + 255) / 256;   // 2 edges/thread
    const int nb  = (N_NODES + 3) / 4;
    const int gb  = (N_NODES + 63) / 64;       // 782 GEMM tiles

    // CSR build (shared by both layers)
    hipMemsetAsync(counts, 0, (size_t)N_NODES * 4, stream);
    k_hist_ei<<<eb2, 256, 0, stream>>>(ei, counts, rank, out_ei);
    k_scan_a<<<SCAN_NB, SCAN_B, 0, stream>>>(counts, blocksum);
    k_scan_b<<<1, SCAN_B, 0, stream>>>(blocksum, rowptr);
    k_scan_c<<<SCAN_NB, SCAN_B, 0, stream>>>(counts, blocksum, rowptr);
    k_scatter<<<eb2, 256, 0, stream>>>(ei, rank, rowptr, csr_eid);

    // layer 1 (hb = bf16 h1)
    k_gemm_t<D_IN><<<gb, 256, 0, stream>>>(x, W1, as1, ad1, hb, es, edv);
    k_agg<true, true><<<nb, 256, 0, stream>>>(hb, es, edv, rowptr, csr_eid, ei,
                                              b1, h1a, out_alpha);
    // layer 2 (hb reused = bf16 h2lin; es/edv reused)
    k_gemm_t<D_HID><<<gb, 256, 0, stream>>>(h1a, W2, as2, ad2, hb, es, edv);
    k_agg<false, false><<<nb, 256, 0, stream>>>(hb, es, edv, rowptr, csr_eid, ei,
                                                b2, out_h2, nullptr);
}

// Round 17
// 255.337 us; speedup vs baseline: 1.2584x; 1.0230x over previous
//
#include <hip/hip_runtime.h>
#include <math.h>

// Problem constants (from reference)
constexpr int N_NODES = 50000;
constexpr int E_EDGES = 800000;
constexpr int E_TOT   = E_EDGES + N_NODES;   // 850000 with self loops
constexpr int D_IN    = 128;
constexpr int D_HID   = 64;   // HID == OUT == 64
constexpr float NEG_SLOPE = 0.2f;
constexpr int NPLANE  = 8;    // XCD count: histogram privatization degree

constexpr int SCAN_B  = 256;
constexpr int SCAN_NB = (N_NODES + SCAN_B - 1) / SCAN_B;   // 196

// bf16 pack (RNE) / unpack — h is stored bf16 for the k_agg gather path
__device__ __forceinline__ unsigned short f2bf(float f) {
    unsigned int u = __float_as_uint(f);
    u += 0x7FFFu + ((u >> 16) & 1u);
    return (unsigned short)(u >> 16);
}
__device__ __forceinline__ float bf2f(unsigned short b) {
    return __uint_as_float(((unsigned int)b) << 16);
}

// ---------------- CSR build ----------------
// Round-16 profile: single shared histogram = 1.7M atomics ping-ponging lines
// across 8 non-coherent XCD L2s (WRITE 35MB vs 10 ideal, 0.5% VALU). Privatize
// 8 planes keyed by blockIdx&7 (cyclic wg->XCD dispatch makes each plane
// XCD-local; correctness holds under ANY mapping).

// one pass, 2 edges/thread: plane histogram + plane-local rank + emit ei
__global__ __launch_bounds__(256)
void k_hist_ei(const int* __restrict__ ei, int* __restrict__ counts8,
               int* __restrict__ rank, float* __restrict__ out_ei) {
    int p = blockIdx.x * blockDim.x + threadIdx.x;
    int k = p * 2;
    if (k >= E_TOT) return;
    int* plane = counts8 + (size_t)(blockIdx.x & (NPLANE - 1)) * N_NODES;
    int s0, d0, s1, d1;
    if (k < E_EDGES) {
        int2 sv = *(const int2*)(ei + k);
        int2 dv = *(const int2*)(ei + E_EDGES + k);
        s0 = sv.x; s1 = sv.y; d0 = dv.x; d1 = dv.y;
    } else {
        s0 = d0 = k - E_EDGES;
        s1 = d1 = k + 1 - E_EDGES;
    }
    *(float2*)(out_ei + k)         = make_float2((float)s0, (float)s1);
    *(float2*)(out_ei + E_TOT + k) = make_float2((float)d0, (float)d1);
    int r0 = atomicAdd(&plane[d0], 1);
    int r1 = atomicAdd(&plane[d1], 1);
    *(int2*)(rank + k) = make_int2(r0, r1);
}

// scan A: per node, convert 8 plane counts -> intra-node exclusive bases
// (in place), total -> counts_tot; block-reduce totals -> blocksum.
__global__ __launch_bounds__(256)
void k_scan_a(int* __restrict__ counts8, int* __restrict__ counts_tot,
              int* __restrict__ blocksum) {
    int i = blockIdx.x * SCAN_B + threadIdx.x;
    int lane = threadIdx.x & 63, wave = threadIdx.x >> 6;
    int tot = 0;
    if (i < N_NODES) {
        int run = 0;
        #pragma unroll
        for (int p = 0; p < NPLANE; ++p) {
            int c = counts8[(size_t)p * N_NODES + i];
            counts8[(size_t)p * N_NODES + i] = run;   // intra-node exclusive base
            run += c;
        }
        tot = run;
        counts_tot[i] = tot;
    }
    int v = tot;
    #pragma unroll
    for (int off = 32; off; off >>= 1) v += __shfl_xor(v, off);
    __shared__ int ws[4];
    if (lane == 0) ws[wave] = v;
    __syncthreads();
    if (threadIdx.x == 0)
        blocksum[blockIdx.x] = ws[0] + ws[1] + ws[2] + ws[3];
}

// scan B: single block scans the 196 block sums (exclusive, in place)
__global__ __launch_bounds__(256)
void k_scan_b(int* __restrict__ blocksum, int* __restrict__ rowptr) {
    __shared__ int s[SCAN_B];
    int t = threadIdx.x;
    int v = (t < SCAN_NB) ? blocksum[t] : 0;
    s[t] = v;
    __syncthreads();
    #pragma unroll
    for (int off = 1; off < SCAN_B; off <<= 1) {
        int u = (t >= off) ? s[t - off] : 0;
        __syncthreads();
        s[t] += u;
        __syncthreads();
    }
    if (t < SCAN_NB) blocksum[t] = s[t] - v;      // exclusive block base
    if (t == SCAN_B - 1) rowptr[N_NODES] = s[SCAN_B - 1];   // total == E_TOT
}

// scan C: rowptr = global exclusive scan; finalize planes to ABSOLUTE bases.
__global__ __launch_bounds__(256)
void k_scan_c(const int* __restrict__ counts_tot, const int* __restrict__ blocksum,
              int* __restrict__ rowptr, int* __restrict__ counts8) {
    __shared__ int s[SCAN_B];
    int t = threadIdx.x;
    int i = blockIdx.x * SCAN_B + t;
    int v = (i < N_NODES) ? counts_tot[i] : 0;
    s[t] = v;
    __syncthreads();
    #pragma unroll
    for (int off = 1; off < SCAN_B; off <<= 1) {
        int u = (t >= off) ? s[t - off] : 0;
        __syncthreads();
        s[t] += u;
        __syncthreads();
    }
    if (i < N_NODES) {
        int base = s[t] - v + blocksum[blockIdx.x];
        rowptr[i] = base;
        #pragma unroll
        for (int p = 0; p < NPLANE; ++p)
            counts8[(size_t)p * N_NODES + i] += base;
    }
}

// scatter, ATOMIC-FREE: same grid geometry as k_hist_ei so p = blockIdx&7
// recovers each edge's plane. pos = abs_base_plane[dst] + plane_rank.
__global__ __launch_bounds__(256)
void k_scatter(const int* __restrict__ ei, const int* __restrict__ rank,
               const int* __restrict__ counts8, int* __restrict__ csr_eid) {
    int p = blockIdx.x * blockDim.x + threadIdx.x;
    int k = p * 2;
    if (k >= E_TOT) return;
    const int* base = counts8 + (size_t)(blockIdx.x & (NPLANE - 1)) * N_NODES;
    int d0, d1;
    if (k < E_EDGES) {
        int2 dv = *(const int2*)(ei + E_EDGES + k);
        d0 = dv.x; d1 = dv.y;
    } else {
        d0 = k - E_EDGES;
        d1 = k + 1 - E_EDGES;
    }
    int2 rv = *(const int2*)(rank + k);
    csr_eid[base[d0] + rv.x] = k;
    csr_eid[base[d1] + rv.y] = k + 1;
}

// ---------------- dense: h = x @ W  (+ per-node attention logits) ----------------
// Register-tiled GEMM -> bf16 h (gather operand) + fp32 es/ed from registers.

template<int K>
__global__ __launch_bounds__(256)
void k_gemm_t(const float* __restrict__ xin, const float* __restrict__ Wg,
              const float* __restrict__ a_s, const float* __restrict__ a_d,
              unsigned short* __restrict__ hb, float* __restrict__ es,
              float* __restrict__ ed) {
    __shared__ float wt[64][K + 4];   // wt[col][k] = Wg[k][col]
    const int t = threadIdx.x;
    const int lane = t & 63, wid = t >> 6;
    for (int k = wid; k < K; k += 4)
        wt[lane][k] = Wg[k * 64 + lane];
    __syncthreads();

    const int cg = t & 15, ng = t >> 4;
    const int c0 = cg * 4;
    const int node0 = blockIdx.x * 64 + ng * 4;
    if (node0 >= N_NODES) return;    // N_NODES % 4 == 0: all-or-nothing per thread
    const float* xrow = xin + (size_t)node0 * K;

    float acc[4][4];
    #pragma unroll
    for (int n = 0; n < 4; ++n)
        #pragma unroll
        for (int i = 0; i < 4; ++i) acc[n][i] = 0.f;

    #pragma unroll 4
    for (int k = 0; k < K; k += 4) {
        float4 xv[4], wv[4];
        #pragma unroll
        for (int n = 0; n < 4; ++n) xv[n] = *(const float4*)(xrow + n * K + k);
        #pragma unroll
        for (int i = 0; i < 4; ++i) wv[i] = *(const float4*)(&wt[c0 + i][k]);
        #pragma unroll
        for (int n = 0; n < 4; ++n) {
            #pragma unroll
            for (int i = 0; i < 4; ++i) {
                acc[n][i] = fmaf(xv[n].x, wv[i].x, acc[n][i]);
                acc[n][i] = fmaf(xv[n].y, wv[i].y, acc[n][i]);
                acc[n][i] = fmaf(xv[n].z, wv[i].z, acc[n][i]);
                acc[n][i] = fmaf(xv[n].w, wv[i].w, acc[n][i]);
            }
        }
    }

    const float4 as4 = *(const float4*)(a_s + c0);
    const float4 ad4 = *(const float4*)(a_d + c0);
    #pragma unroll
    for (int n = 0; n < 4; ++n) {
        ushort4 hv4;
        hv4.x = f2bf(acc[n][0]); hv4.y = f2bf(acc[n][1]);
        hv4.z = f2bf(acc[n][2]); hv4.w = f2bf(acc[n][3]);
        *(ushort4*)(hb + (size_t)(node0 + n) * D_HID + c0) = hv4;
        float vs = acc[n][0] * as4.x + acc[n][1] * as4.y
                 + acc[n][2] * as4.z + acc[n][3] * as4.w;
        float vd = acc[n][0] * ad4.x + acc[n][1] * ad4.y
                 + acc[n][2] * ad4.z + acc[n][3] * ad4.w;
        #pragma unroll
        for (int off = 8; off; off >>= 1) {   // butterfly across the 16 col-lanes
            vs += __shfl_xor(vs, off);
            vd += __shfl_xor(vd, off);
        }
        if (cg == 0) { es[node0 + n] = vs; ed[node0 + n] = vd; }
    }
}

// ---------------- sparse: segment softmax + weighted aggregation ----------------
// one wave per destination node; src derived from csr_eid via ei; bf16 h gather.

template<bool RELU, bool WRITE_ALPHA>
__global__ __launch_bounds__(256)
void k_agg(const unsigned short* __restrict__ hb, const float* __restrict__ es,
           const float* __restrict__ ed, const int* __restrict__ rowptr,
           const int* __restrict__ csr_eid, const int* __restrict__ ei,
           const float* __restrict__ bias, float* __restrict__ out,
           float* __restrict__ alpha_out) {
    int wave = threadIdx.x >> 6, lane = threadIdx.x & 63;
    int node = blockIdx.x * 4 + wave;
    if (node >= N_NODES) return;
    int lo  = __builtin_amdgcn_readfirstlane(rowptr[node]);
    int deg = __builtin_amdgcn_readfirstlane(rowptr[node + 1]) - lo;
    float edv = ed[node];

    if (deg <= 64) {
        // ---- fast path: lane-parallel logits, register-resident softmax ----
        int   s = 0, eid = 0;
        float e = -INFINITY;
        if (lane < deg) {
            eid = csr_eid[lo + lane];
            s   = (eid < E_EDGES) ? ei[eid] : (eid - E_EDGES);
            e = es[s] + edv;
            e = (e >= 0.f) ? e : NEG_SLOPE * e;
        }
        float m = e;
        #pragma unroll
        for (int off = 32; off; off >>= 1) m = fmaxf(m, __shfl_xor(m, off));
        float ex = (lane < deg) ? __expf(e - m) : 0.f;
        float z = ex;
        #pragma unroll
        for (int off = 32; off; off >>= 1) z += __shfl_xor(z, off);
        float inv = 1.f / z;

        // 8 independent load/fma chains
        float a0 = 0.f, a1 = 0.f, a2 = 0.f, a3 = 0.f;
        float a4 = 0.f, a5 = 0.f, a6 = 0.f, a7 = 0.f;
        int j = 0;
        for (; j + 8 <= deg; j += 8) {
            int   s0 = __shfl(s, j),     s1 = __shfl(s, j + 1);
            int   s2 = __shfl(s, j + 2), s3 = __shfl(s, j + 3);
            int   s4 = __shfl(s, j + 4), s5 = __shfl(s, j + 5);
            int   s6 = __shfl(s, j + 6), s7 = __shfl(s, j + 7);
            float e0 = __shfl(ex, j),     e1 = __shfl(ex, j + 1);
            float e2 = __shfl(ex, j + 2), e3 = __shfl(ex, j + 3);
            float e4 = __shfl(ex, j + 4), e5 = __shfl(ex, j + 5);
            float e6 = __shfl(ex, j + 6), e7 = __shfl(ex, j + 7);
            a0 = fmaf(e0, bf2f(hb[s0 * D_HID + lane]), a0);
            a1 = fmaf(e1, bf2f(hb[s1 * D_HID + lane]), a1);
            a2 = fmaf(e2, bf2f(hb[s2 * D_HID + lane]), a2);
            a3 = fmaf(e3, bf2f(hb[s3 * D_HID + lane]), a3);
            a4 = fmaf(e4, bf2f(hb[s4 * D_HID + lane]), a4);
            a5 = fmaf(e5, bf2f(hb[s5 * D_HID + lane]), a5);
            a6 = fmaf(e6, bf2f(hb[s6 * D_HID + lane]), a6);
            a7 = fmaf(e7, bf2f(hb[s7 * D_HID + lane]), a7);
        }
        for (; j + 4 <= deg; j += 4) {
            int   s0 = __shfl(s, j),     s1 = __shfl(s, j + 1);
            int   s2 = __shfl(s, j + 2), s3 = __shfl(s, j + 3);
            float e0 = __shfl(ex, j),     e1 = __shfl(ex, j + 1);
            float e2 = __shfl(ex, j + 2), e3 = __shfl(ex, j + 3);
            a0 = fmaf(e0, bf2f(hb[s0 * D_HID + lane]), a0);
            a1 = fmaf(e1, bf2f(hb[s1 * D_HID + lane]), a1);
            a2 = fmaf(e2, bf2f(hb[s2 * D_HID + lane]), a2);
            a3 = fmaf(e3, bf2f(hb[s3 * D_HID + lane]), a3);
        }
        for (; j < deg; ++j) {
            int   sj  = __shfl(s, j);
            float exj = __shfl(ex, j);
            a0 = fmaf(exj, bf2f(hb[sj * D_HID + lane]), a0);
        }
        float acc = ((a0 + a1) + (a2 + a3)) + ((a4 + a5) + (a6 + a7));
        float res = fmaf(acc, inv, bias[lane]);
        if (RELU) res = fmaxf(res, 0.f);
        out[node * D_HID + lane] = res;
        if (WRITE_ALPHA && lane < deg) alpha_out[eid] = ex * inv;
    } else {
        // ---- fallback: serial 3-pass (degree > 64; effectively never) ----
        int hi = lo + deg;
        float m = -INFINITY;
        for (int j = lo; j < hi; ++j) {
            int eid = csr_eid[j];
            int s   = (eid < E_EDGES) ? ei[eid] : (eid - E_EDGES);
            float e = es[s] + edv;
            e = (e >= 0.f) ? e : NEG_SLOPE * e;
            m = fmaxf(m, e);
        }
        float z = 0.f, acc = 0.f;
        for (int j = lo; j < hi; ++j) {
            int eid = csr_eid[j];
            int s   = (eid < E_EDGES) ? ei[eid] : (eid - E_EDGES);
            float e = es[s] + edv;
            e = (e >= 0.f) ? e : NEG_SLOPE * e;
            float ex = __expf(e - m);
            z += ex;
            acc = fmaf(ex, bf2f(hb[s * D_HID + lane]), acc);
        }
        float inv = 1.f / z;
        float res = fmaf(acc, inv, bias[lane]);
        if (RELU) res = fmaxf(res, 0.f);
        out[node * D_HID + lane] = res;
        if (WRITE_ALPHA) {
            for (int j = lo + lane; j < hi; j += 64) {
                int eid = csr_eid[j];
                int s   = (eid < E_EDGES) ? ei[eid] : (eid - E_EDGES);
                float e = es[s] + edv;
                e = (e >= 0.f) ? e : NEG_SLOPE * e;
                alpha_out[eid] = __expf(e - m) * inv;
            }
        }
    }
}

// ---------------- launch ----------------

extern "C" void kernel_launch(void* const* d_in, const int* in_sizes, int n_in,
                              void* d_out, int out_size, void* d_ws, size_t ws_size,
                              hipStream_t stream) {
    const float* x    = (const float*)d_in[0];
    const int*   ei   = (const int*)d_in[1];
    const float* W1   = (const float*)d_in[2];
    const float* as1  = (const float*)d_in[3];
    const float* ad1  = (const float*)d_in[4];
    const float* b1   = (const float*)d_in[5];
    const float* W2   = (const float*)d_in[6];
    const float* as2  = (const float*)d_in[7];
    const float* ad2  = (const float*)d_in[8];
    const float* b2   = (const float*)d_in[9];
    float* out = (float*)d_out;

    // carve workspace (~29 MB)
    size_t off = 0;
    auto carve = [&](size_t bytes) -> void* {
        void* p = (char*)d_ws + off;
        off += (bytes + 255) & ~(size_t)255;
        return p;
    };
    int*            counts8   = (int*)carve((size_t)NPLANE * N_NODES * 4);
    int*            counts_tot= (int*)carve((size_t)N_NODES * 4);
    int*            rowptr    = (int*)carve((size_t)(N_NODES + 1) * 4);
    int*            blocksum  = (int*)carve((size_t)SCAN_NB * 4);
    int*            rank      = (int*)carve((size_t)E_TOT * 4);
    int*            csr_eid   = (int*)carve((size_t)E_TOT * 4);
    unsigned short* hb        = (unsigned short*)carve((size_t)N_NODES * D_HID * 2);
    float*          h1a       = (float*)carve((size_t)N_NODES * D_HID * 4);
    float*          es        = (float*)carve((size_t)N_NODES * 4);
    float*          edv       = (float*)carve((size_t)N_NODES * 4);

    float* out_ei    = out;                     // [2*E_TOT]
    float* out_alpha = out + 2 * (size_t)E_TOT; // [E_TOT]
    float* out_h2    = out + 3 * (size_t)E_TOT; // [N*64]

    const int eb2 = (E_TOT / 2 + 255) / 256;   // 2 edges/thread (hist & scatter!)
    const int nb  = (N_NODES + 3) / 4;
    const int gb  = (N_NODES + 63) / 64;       // 782 GEMM tiles

    // CSR build (shared by both layers)
    hipMemsetAsync(counts8, 0, (size_t)NPLANE * N_NODES * 4, stream);
    k_hist_ei<<<eb2, 256, 0, stream>>>(ei, counts8, rank, out_ei);
    k_scan_a<<<SCAN_NB, SCAN_B, 0, stream>>>(counts8, counts_tot, blocksum);
    k_scan_b<<<1, SCAN_B, 0, stream>>>(blocksum, rowptr);
    k_scan_c<<<SCAN_NB, SCAN_B, 0, stream>>>(counts_tot, blocksum, rowptr, counts8);
    k_scatter<<<eb2, 256, 0, stream>>>(ei, rank, counts8, csr_eid);

    // layer 1 (hb = bf16 h1)
    k_gemm_t<D_IN><<<gb, 256, 0, stream>>>(x, W1, as1, ad1, hb, es, edv);
    k_agg<true, true><<<nb, 256, 0, stream>>>(hb, es, edv, rowptr, csr_eid, ei,
                                              b1, h1a, out_alpha);
    // layer 2 (hb reused = bf16 h2lin; es/edv reused)
    k_gemm_t<D_HID><<<gb, 256, 0, stream>>>(h1a, W2, as2, ad2, hb, es, edv);
    k_agg<false, false><<<nb, 256, 0, stream>>>(hb, es, edv, rowptr, csr_eid, ei,
                                                b2, out_h2, nullptr);
}